// Round 13
// baseline (1313.756 us; speedup 1.0000x reference)
//
#include <hip/hip_runtime.h>
#include <hip/hip_bf16.h>
#include <math.h>

#define S 512
#define B 2
#define D 768
#define H 12
#define DH 64
#define DI 3072
#define NL 12
#define NTOK (S * B)   // 1024

typedef __attribute__((ext_vector_type(8))) short short8v;
typedef __attribute__((ext_vector_type(4))) float f32x4;

__device__ __forceinline__ unsigned short f2b(float f) {
  union { float f; unsigned int u; } v; v.f = f;
  unsigned int r = v.u + 0x7fffu + ((v.u >> 16) & 1u);
  return (unsigned short)(r >> 16);
}
__device__ __forceinline__ float b2f(unsigned short u) {
  union { unsigned int u; float f; } v; v.u = ((unsigned int)u) << 16;
  return v.f;
}

__device__ __forceinline__ float gelu_f(float x) {
  const float c = 0.7978845608028654f;  // sqrt(2/pi)
  float t = tanhf(c * (x + 0.044715f * x * x * x));
  return x * 0.5f * (1.0f + t);
}

// xor swizzle key for bf16 LDS tiles with 64-ushort rows (8-ushort granular)
__device__ __forceinline__ int vkey(int r) {
  return ((((r & 7) ^ ((r >> 3) & 7)) & 7) << 3);
}

// ---------------- embedding gather ----------------
__global__ __launch_bounds__(256) void embed_kernel(const int* __restrict__ inp_k,
                                                    const float* __restrict__ lut,
                                                    float* __restrict__ h,
                                                    unsigned short* __restrict__ h_bf) {
  int t = blockIdx.x;
  int id = inp_k[t];
  for (int j = threadIdx.x; j < D; j += 256) {
    float v = lut[(size_t)id * D + j];
    h[t * D + j] = v;
    h_bf[t * D + j] = f2b(v);
  }
}

// ---------------- positional embedding -> bf16 [2S, D] ----------------
__global__ __launch_bounds__(384) void posemb_kernel(unsigned short* __restrict__ r2b) {
  int j = blockIdx.x;
  int d = threadIdx.x;
  float pos = (float)(S - j);
  float inv_freq = expf(-logf(10000.0f) * (2.0f * (float)d / (float)D));
  float x = pos * inv_freq;
  r2b[j * D + d]       = f2b(sinf(x));
  r2b[j * D + 384 + d] = f2b(cosf(x));
}

// ===== weight prep: coalesced f32 reads + conflict-free LDS transpose =========
__device__ __forceinline__ void transpose_swz(const float* __restrict__ src,   // [K][N] row-major
                                              unsigned short* __restrict__ dst,
                                              int K, int N, int tile, int n_base,
                                              float* __restrict__ Ls /*[64*65]*/) {
  int ntk = K >> 6;
  int tk = tile % ntk, tn = tile / ntk;
  int k0 = tk << 6, n0 = tn << 6;
  int tid = threadIdx.x;
  int rr = tid >> 4, c4 = (tid & 15) * 4;
#pragma unroll
  for (int r = 0; r < 4; ++r) {
    int k = rr + r * 16;
    float4 a = *(const float4*)&src[(size_t)(k0 + k) * N + n0 + c4];
    Ls[(c4 + 0) * 65 + k] = a.x;
    Ls[(c4 + 1) * 65 + k] = a.y;
    Ls[(c4 + 2) * 65 + k] = a.z;
    Ls[(c4 + 3) * 65 + k] = a.w;
  }
  __syncthreads();
  int nl = tid >> 2, kc0 = (tid & 3) << 4;
  float f[16];
#pragma unroll
  for (int c = 0; c < 16; ++c) f[c] = Ls[nl * 65 + kc0 + c];
  short8v v0, v1;
#pragma unroll
  for (int e = 0; e < 8; ++e) {
    v0[e] = (short)f2b(f[e]);
    v1[e] = (short)f2b(f[8 + e]);
  }
  int ng = n_base + n0;
  size_t tilebase = ((size_t)(ng >> 7) * ntk + tk) * 8192;
  int row = (ng & 64) + nl;
  int key = (row & 7) << 3;
  *(short8v*)&dst[tilebase + row * 64 + (kc0 ^ key)] = v0;
  *(short8v*)&dst[tilebase + row * 64 + ((kc0 + 8) ^ key)] = v1;
}

// per layer: 432 qkv + 144 wr + 576 w1 + 576 w2 + 144 wo = 1872 blocks
__global__ __launch_bounds__(256) void prep_all(const float* __restrict__ Wq,
                                                const float* __restrict__ Wk,
                                                const float* __restrict__ Wv,
                                                const float* __restrict__ Wr,
                                                const float* __restrict__ Wo,
                                                const float* __restrict__ W1,
                                                const float* __restrict__ W2,
                                                unsigned short* __restrict__ wqkv_t,
                                                unsigned short* __restrict__ wr_t,
                                                unsigned short* __restrict__ wo_t,
                                                unsigned short* __restrict__ w1_t,
                                                unsigned short* __restrict__ w2_t) {
  __shared__ float Ls[64 * 65];
  const size_t DD = (size_t)D * D;
  const size_t DDI = (size_t)D * DI;
  int tb = blockIdx.x;
  int l = tb / 1872, t2 = tb % 1872;
  int tid = threadIdx.x;
  if (t2 < 432) {
    int which = t2 / 144, tile = t2 % 144;
    const float* src = (which == 0 ? Wq : (which == 1 ? Wk : Wv)) + l * DD;
    transpose_swz(src, wqkv_t + l * 3 * DD, D, D, tile, which * D, Ls);
  } else if (t2 < 576) {
    transpose_swz(Wr + l * DD, wr_t + l * DD, D, D, t2 - 432, 0, Ls);
  } else if (t2 < 1152) {
    transpose_swz(W1 + l * DDI, w1_t + l * DDI, D, DI, t2 - 576, 0, Ls);
  } else if (t2 < 1728) {
    transpose_swz(W2 + l * DDI, w2_t + l * DDI, DI, D, t2 - 1152, 0, Ls);
  } else {
    // Wo: already [N][K]; swizzle-copy
    int c = t2 - 1728;
    int tkk = c % 12, tnn = c / 12;
    int k0 = tkk << 6, n0 = tnn << 6;
    int nl = tid >> 2, kc0 = (tid & 3) << 4;
    const float* srcp = Wo + l * DD + (size_t)(n0 + nl) * D + k0 + kc0;
    float4 a0 = *(const float4*)&srcp[0];
    float4 a1 = *(const float4*)&srcp[4];
    float4 a2 = *(const float4*)&srcp[8];
    float4 a3 = *(const float4*)&srcp[12];
    short8v v0, v1;
    v0[0] = (short)f2b(a0.x); v0[1] = (short)f2b(a0.y); v0[2] = (short)f2b(a0.z); v0[3] = (short)f2b(a0.w);
    v0[4] = (short)f2b(a1.x); v0[5] = (short)f2b(a1.y); v0[6] = (short)f2b(a1.z); v0[7] = (short)f2b(a1.w);
    v1[0] = (short)f2b(a2.x); v1[1] = (short)f2b(a2.y); v1[2] = (short)f2b(a2.z); v1[3] = (short)f2b(a2.w);
    v1[4] = (short)f2b(a3.x); v1[5] = (short)f2b(a3.y); v1[6] = (short)f2b(a3.z); v1[7] = (short)f2b(a3.w);
    unsigned short* dst = wo_t + l * DD;
    size_t tilebase = ((size_t)(n0 >> 7) * 12 + tkk) * 8192;
    int row = (n0 & 64) + nl;
    int key = (row & 7) << 3;
    *(short8v*)&dst[tilebase + row * 64 + (kc0 ^ key)] = v0;
    *(short8v*)&dst[tilebase + row * 64 + ((kc0 + 8) ^ key)] = v1;
  }
}

// ======================= MFMA GEMM (global_load_lds + swizzle) ================
template <int ACT, int OUTBF>
__device__ __forceinline__ void gemm_tile(const unsigned short* __restrict__ A,
                                          const unsigned short* __restrict__ Wt,
                                          const float* __restrict__ bias,
                                          float* __restrict__ Cf,
                                          unsigned short* __restrict__ Cb,
                                          int N, int K, int bm, int bn,
                                          int kbeg, int kend) {
  __shared__ __align__(16) unsigned short As[64 * 64];
  __shared__ __align__(16) unsigned short Bs[128 * 64];
  const int tid = threadIdx.x, lane = tid & 63, w = tid >> 6;
  const int l8 = lane >> 3, lm8 = lane & 7;
  const int aColByte = ((lm8 ^ l8) << 4);
  const int KT = K >> 6;
  const size_t wtn = (size_t)(bn >> 7) * KT;

  f32x4 acc[4][2];
#pragma unroll
  for (int mi = 0; mi < 4; ++mi)
#pragma unroll
    for (int ni = 0; ni < 2; ++ni)
      acc[mi][ni] = (f32x4){0.f, 0.f, 0.f, 0.f};

  for (int kt = kbeg; kt < kend; kt += 64) {
    __syncthreads();
#pragma unroll
    for (int c = 0; c < 2; ++c) {
      int row = c * 32 + w * 8 + l8;
      const char* src = (const char*)&A[(size_t)(bm + row) * K + kt] + aColByte;
      __builtin_amdgcn_global_load_lds(
          (const __attribute__((address_space(1))) void*)src,
          (__attribute__((address_space(3))) void*)((char*)As + c * 4096 + w * 1024),
          16, 0, 0);
    }
    const char* wt = (const char*)&Wt[(wtn + (kt >> 6)) * 8192];
#pragma unroll
    for (int c = 0; c < 4; ++c) {
      __builtin_amdgcn_global_load_lds(
          (const __attribute__((address_space(1))) void*)(wt + c * 4096 + w * 1024 + lane * 16),
          (__attribute__((address_space(3))) void*)((char*)Bs + c * 4096 + w * 1024),
          16, 0, 0);
    }
    __syncthreads();
#pragma unroll
    for (int ks = 0; ks < 2; ++ks) {
      const int kus = ks * 32 + (lane >> 4) * 8;
      short8v af[4], bf[2];
#pragma unroll
      for (int mi = 0; mi < 4; ++mi) {
        int row = mi * 16 + (lane & 15);
        af[mi] = *(const short8v*)&As[row * 64 + (kus ^ ((row & 7) << 3))];
      }
#pragma unroll
      for (int ni = 0; ni < 2; ++ni) {
        int row = w * 32 + ni * 16 + (lane & 15);
        bf[ni] = *(const short8v*)&Bs[row * 64 + (kus ^ ((row & 7) << 3))];
      }
#pragma unroll
      for (int mi = 0; mi < 4; ++mi)
#pragma unroll
        for (int ni = 0; ni < 2; ++ni)
          acc[mi][ni] = __builtin_amdgcn_mfma_f32_16x16x32_bf16(af[mi], bf[ni], acc[mi][ni], 0, 0, 0);
    }
  }

  int r0 = (lane >> 4) * 4, cc = lane & 15;
#pragma unroll
  for (int mi = 0; mi < 4; ++mi) {
    int row = bm + mi * 16 + r0;
#pragma unroll
    for (int ni = 0; ni < 2; ++ni) {
      int col = bn + w * 32 + ni * 16 + cc;
      float bv = bias ? bias[col] : 0.0f;
#pragma unroll
      for (int r = 0; r < 4; ++r) {
        float v = acc[mi][ni][r] + bv;
        if (ACT == 1) v = gelu_f(v);
        if (OUTBF) Cb[(size_t)(row + r) * N + col] = f2b(v);
        else       Cf[(size_t)(row + r) * N + col] = v;
      }
    }
  }
}

// qkv projection only: grid.x = 288
__global__ __launch_bounds__(256) void gemm_qkv(const unsigned short* __restrict__ h_bf,
                                                const unsigned short* __restrict__ wqkv,
                                                unsigned short* __restrict__ qkv_bf) {
  int bx = blockIdx.x;
  gemm_tile<0, 1>(h_bf, wqkv, nullptr, nullptr, qkv_bf, 2304, 768,
                  (bx / 18) * 64, (bx % 18) * 128, 0, 768);
}

// kr projections for ALL layers upfront: grid.x = 12 * 96 = 1152
__global__ __launch_bounds__(256) void gemm_kr_all(const unsigned short* __restrict__ r2_bf,
                                                   const unsigned short* __restrict__ wr_t,
                                                   unsigned short* __restrict__ kr_all) {
  int bx = blockIdx.x;
  int l = bx / 96, b2 = bx % 96;
  gemm_tile<0, 1>(r2_bf, wr_t + (size_t)l * D * D, nullptr, nullptr,
                  kr_all + (size_t)l * NTOK * D, 768, 768,
                  (b2 / 6) * 64, (b2 % 6) * 128, 0, 768);
}

template <int ACT>
__global__ __launch_bounds__(256) void gemm_bias(const unsigned short* __restrict__ A,
                                                 const unsigned short* __restrict__ W,
                                                 const float* __restrict__ bias,
                                                 unsigned short* __restrict__ C,
                                                 int N, int K, int ncb) {
  int bx = blockIdx.x;
  gemm_tile<ACT, 1>(A, W, bias, nullptr, C, N, K, (bx / ncb) * 64, (bx % ncb) * 128, 0, K);
}

__global__ __launch_bounds__(256) void gemm_splitk(const unsigned short* __restrict__ A,
                                                   const unsigned short* __restrict__ W,
                                                   float* __restrict__ part,
                                                   int N, int K, int kch) {
  int kz = blockIdx.z;
  float* Cf = part + (size_t)kz * NTOK * N;
  gemm_tile<0, 0>(A, W, nullptr, Cf, nullptr, N, K,
                  blockIdx.y * 64, blockIdx.x * 128, kz * kch, (kz + 1) * kch);
}

// ============ MFMA fused attention, 32-row i-tile, online softmax =============
// K/KR staged via global_load_lds into linear [rows][64] LDS with XOR key
// ((row&7)<<3); source pre-swizzled per-lane (same involution).
__global__ __launch_bounds__(256) void attn_kernel(const unsigned short* __restrict__ qkv,
                                                   const unsigned short* __restrict__ krb,
                                                   const int* __restrict__ seg_ids,
                                                   const int* __restrict__ input_mask,
                                                   const float* __restrict__ rwb,
                                                   const float* __restrict__ rrb,
                                                   const float* __restrict__ rsb,
                                                   const float* __restrict__ segemb,
                                                   unsigned short* __restrict__ vec_bf) {
  __shared__ __align__(16) char smem[49280];
  unsigned short* qw_s = (unsigned short*)(smem + 0);       // [32][72]
  unsigned short* qr_s = (unsigned short*)(smem + 4608);    // [32][72]
  unsigned short* k_s  = (unsigned short*)(smem + 9216);    // [64][64] linear+xor
  unsigned short* kr_s = (unsigned short*)(smem + 17408);   // [96][64] linear+xor
  unsigned short* bd_s = (unsigned short*)(smem + 29696);   // [32][104]
  unsigned short* vt_s = (unsigned short*)(smem + 36352);   // [64][64] xor
  unsigned short* pb_s = (unsigned short*)(smem + 44544);   // [32][64] xor
  float* sc_s  = (float*)(smem + 9216);                     // [32][68] f32, aliases k_s/kr_s head
  float* efs    = (float*)(smem + 48640);                   // [2][32]
  float* frow_s = (float*)(smem + 48896);                   // [32]
  float* rinv_s = (float*)(smem + 49024);                   // [32]
  int*   segrow = (int*)(smem + 49152);                     // [32]

  const int it = blockIdx.x * 32, b = blockIdx.y, n = blockIdx.z;
  const int tid = threadIdx.x, lane = tid & 63, w = tid >> 6;
  const int l8 = lane >> 3, lm8 = lane & 7;
  const int aColByte = ((lm8 ^ l8) << 4);
  const int rdkey = ((lane & 7) << 3);   // read-side xor key (row&7 == lane&7 for our rows)

  {
    int il = tid >> 3, d8 = (tid & 7) * 8;
    int t = (it + il) * B + b;
    short8v q0 = *(const short8v*)&qkv[(size_t)t * 2304 + n * 64 + d8];
    short8v ow0, or0;
#pragma unroll
    for (int e = 0; e < 8; ++e) {
      float f0 = b2f((unsigned short)q0[e]);
      ow0[e] = (short)f2b(f0 + rwb[n * 64 + d8 + e]);
      or0[e] = (short)f2b(f0 + rrb[n * 64 + d8 + e]);
    }
    *(short8v*)&qw_s[il * 72 + d8] = ow0;
    *(short8v*)&qr_s[il * 72 + d8] = or0;
  }
  if (tid < 64) {
    int il = tid >> 1, s = tid & 1;
    int t = (it + il) * B + b;
    float acc = 0.0f;
    for (int d = 0; d < 64; ++d)
      acc = fmaf(b2f(qkv[(size_t)t * 2304 + n * 64 + d]) + rsb[n * 64 + d],
                 segemb[(s * H + n) * 64 + d], acc);
    efs[s * 32 + il] = acc;
  }
  if (tid < 32) segrow[tid] = seg_ids[(it + tid) * B + b];

  // stage tile 0 K (64 rows) / KR (96 rows) via global_load_lds
  {
#pragma unroll
    for (int c = 0; c < 2; ++c) {
      int row = c * 32 + w * 8 + l8;
      const char* src = (const char*)&qkv[(size_t)(row * B + b) * 2304 + 768 + n * 64] + aColByte;
      __builtin_amdgcn_global_load_lds(
          (const __attribute__((address_space(1))) void*)src,
          (__attribute__((address_space(3))) void*)((char*)k_s + c * 4096 + w * 1024),
          16, 0, 0);
    }
    int u0 = 481 - it;
#pragma unroll
    for (int c = 0; c < 3; ++c) {
      int row = c * 32 + w * 8 + l8;
      const char* src = (const char*)&krb[(size_t)(u0 + row) * 768 + n * 64] + aColByte;
      __builtin_amdgcn_global_load_lds(
          (const __attribute__((address_space(1))) void*)src,
          (__attribute__((address_space(3))) void*)((char*)kr_s + c * 4096 + w * 1024),
          16, 0, 0);
    }
  }

  f32x4 acc_v[2];
  acc_v[0] = (f32x4){0.f, 0.f, 0.f, 0.f};
  acc_v[1] = (f32x4){0.f, 0.f, 0.f, 0.f};
  float m_run = -3.0e38f;
  float rsq = 0.0f;
  const int srow = tid >> 3, sc0 = (tid & 7) * 8;

  __syncthreads();   // T1 (drains staging vmcnt)

  for (int jt = 0; jt < 512; jt += 64) {
    const int vj = tid >> 2, vd16 = (tid & 3) * 16;
    short8v vl0 = *(const short8v*)&qkv[(size_t)((jt + vj) * B + b) * 2304 + 1536 + n * 64 + vd16];
    short8v vl1 = *(const short8v*)&qkv[(size_t)((jt + vj) * B + b) * 2304 + 1536 + n * 64 + vd16 + 8];

    f32x4 jacc[3][2];
#pragma unroll
    for (int t = 0; t < 3; ++t) {
      jacc[t][0] = (f32x4){0.f, 0.f, 0.f, 0.f};
      jacc[t][1] = (f32x4){0.f, 0.f, 0.f, 0.f};
    }
#pragma unroll
    for (int ks = 0; ks < 2; ++ks) {
      int kb = ks * 32 + (lane >> 4) * 8;
      int kk = kb ^ rdkey;
      short8v aw[2], ar[2];
#pragma unroll
      for (int mi = 0; mi < 2; ++mi) {
        aw[mi] = *(const short8v*)&qw_s[(mi * 16 + (lane & 15)) * 72 + kb];
        ar[mi] = *(const short8v*)&qr_s[(mi * 16 + (lane & 15)) * 72 + kb];
      }
      {
        short8v bk = *(const short8v*)&k_s[(w * 16 + (lane & 15)) * 64 + kk];
        jacc[0][0] = __builtin_amdgcn_mfma_f32_16x16x32_bf16(aw[0], bk, jacc[0][0], 0, 0, 0);
        jacc[0][1] = __builtin_amdgcn_mfma_f32_16x16x32_bf16(aw[1], bk, jacc[0][1], 0, 0, 0);
      }
      {
        short8v br = *(const short8v*)&kr_s[(w * 16 + (lane & 15)) * 64 + kk];
        jacc[1][0] = __builtin_amdgcn_mfma_f32_16x16x32_bf16(ar[0], br, jacc[1][0], 0, 0, 0);
        jacc[1][1] = __builtin_amdgcn_mfma_f32_16x16x32_bf16(ar[1], br, jacc[1][1], 0, 0, 0);
      }
      if (w < 2) {
        short8v br = *(const short8v*)&kr_s[((w + 4) * 16 + (lane & 15)) * 64 + kk];
        jacc[2][0] = __builtin_amdgcn_mfma_f32_16x16x32_bf16(ar[0], br, jacc[2][0], 0, 0, 0);
        jacc[2][1] = __builtin_amdgcn_mfma_f32_16x16x32_bf16(ar[1], br, jacc[2][1], 0, 0, 0);
      }
    }
#pragma unroll
    for (int t = 1; t < 3; ++t) {
      int cf = w + (t - 1) * 4;
      if (t == 1 || w < 2) {
#pragma unroll
        for (int mi = 0; mi < 2; ++mi)
#pragma unroll
          for (int r = 0; r < 4; ++r)
            bd_s[(mi * 16 + (lane >> 4) * 4 + r) * 104 + cf * 16 + (lane & 15)] =
                f2b(jacc[t][mi][r]);
      }
    }
    __syncthreads();   // T2

    {
      int jl = w * 16 + (lane & 15);
      int jg = jt + jl;
      float maskterm = -1e30f * (float)input_mask[jg * B + b];
      int segj = seg_ids[jg * B + b];
#pragma unroll
      for (int mi = 0; mi < 2; ++mi)
#pragma unroll
        for (int r = 0; r < 4; ++r) {
          int il = mi * 16 + (lane >> 4) * 4 + r;
          float bd = b2f(bd_s[il * 104 + 31 - il + jl]);
          float e = efs[(segrow[il] != segj ? 1 : 0) * 32 + il];
          sc_s[il * 68 + jl] = (jacc[0][mi][r] + bd + e) * 0.125f + maskterm;
        }
    }
    __syncthreads();   // T3

    {
      float4 f0 = *(const float4*)&sc_s[srow * 68 + sc0];
      float4 f1 = *(const float4*)&sc_s[srow * 68 + sc0 + 4];
      float mx = fmaxf(fmaxf(fmaxf(f0.x, f0.y), fmaxf(f0.z, f0.w)),
                       fmaxf(fmaxf(f1.x, f1.y), fmaxf(f1.z, f1.w)));
      mx = fmaxf(mx, __shfl_xor(mx, 1, 8));
      mx = fmaxf(mx, __shfl_xor(mx, 2, 8));
      mx = fmaxf(mx, __shfl_xor(mx, 4, 8));
      float mnew = fmaxf(m_run, mx);
      float fsc = __expf(m_run - mnew);
      m_run = mnew;
      float p0 = __expf(f0.x - mnew), p1 = __expf(f0.y - mnew);
      float p2 = __expf(f0.z - mnew), p3 = __expf(f0.w - mnew);
      float p4 = __expf(f1.x - mnew), p5 = __expf(f1.y - mnew);
      float p6 = __expf(f1.z - mnew), p7 = __expf(f1.w - mnew);
      rsq = rsq * fsc + ((p0 + p1 + p2 + p3) + (p4 + p5 + p6 + p7));
      short8v o0;
      o0[0] = (short)f2b(p0); o0[1] = (short)f2b(p1); o0[2] = (short)f2b(p2); o0[3] = (short)f2b(p3);
      o0[4] = (short)f2b(p4); o0[5] = (short)f2b(p5); o0[6] = (short)f2b(p6); o0[7] = (short)f2b(p7);
      *(short8v*)&pb_s[srow * 64 + (sc0 ^ vkey(srow))] = o0;
      if ((tid & 7) == 0) frow_s[srow] = fsc;
#pragma unroll
      for (int e = 0; e < 8; ++e) {
        int d0 = vd16 + e, d1 = vd16 + 8 + e;
        vt_s[d0 * 64 + (vj ^ vkey(d0))] = (unsigned short)vl0[e];
        vt_s[d1 * 64 + (vj ^ vkey(d1))] = (unsigned short)vl1[e];
      }
    }
    __syncthreads();   // T4

#pragma unroll
    for (int mi = 0; mi < 2; ++mi) {
#pragma unroll
      for (int r = 0; r < 4; ++r)
        acc_v[mi][r] *= frow_s[mi * 16 + (lane >> 4) * 4 + r];
    }
#pragma unroll
    for (int ks = 0; ks < 2; ++ks) {
      int kb = ks * 32 + (lane >> 4) * 8;
      int vrow = w * 16 + (lane & 15);
      short8v bv = *(const short8v*)&vt_s[vrow * 64 + (kb ^ vkey(vrow))];
#pragma unroll
      for (int mi = 0; mi < 2; ++mi) {
        int prow = mi * 16 + (lane & 15);
        short8v ap = *(const short8v*)&pb_s[prow * 64 + (kb ^ vkey(prow))];
        acc_v[mi] = __builtin_amdgcn_mfma_f32_16x16x32_bf16(ap, bv, acc_v[mi], 0, 0, 0);
      }
    }
    if (jt < 448) {
      int jn = jt + 64;
#pragma unroll
      for (int c = 0; c < 2; ++c) {
        int row = c * 32 + w * 8 + l8;
        const char* src = (const char*)&qkv[(size_t)((jn + row) * B + b) * 2304 + 768 + n * 64] + aColByte;
        __builtin_amdgcn_global_load_lds(
            (const __attribute__((address_space(1))) void*)src,
            (__attribute__((address_space(3))) void*)((char*)k_s + c * 4096 + w * 1024),
            16, 0, 0);
      }
      int u0 = 481 - it + jn;
#pragma unroll
      for (int c = 0; c < 3; ++c) {
        int row = c * 32 + w * 8 + l8;
        const char* src = (const char*)&krb[(size_t)(u0 + row) * 768 + n * 64] + aColByte;
        __builtin_amdgcn_global_load_lds(
            (const __attribute__((address_space(1))) void*)src,
            (__attribute__((address_space(3))) void*)((char*)kr_s + c * 4096 + w * 1024),
            16, 0, 0);
      }
    }
    __syncthreads();   // T1 (next; drains staging vmcnt)
  }

  {
    float tot = rsq;
    tot += __shfl_xor(tot, 1, 8);
    tot += __shfl_xor(tot, 2, 8);
    tot += __shfl_xor(tot, 4, 8);
    if ((tid & 7) == 0) rinv_s[srow] = 1.0f / tot;
  }
  __syncthreads();

#pragma unroll
  for (int mi = 0; mi < 2; ++mi)
#pragma unroll
    for (int r = 0; r < 4; ++r) {
      int row = mi * 16 + (lane >> 4) * 4 + r;
      int d = w * 16 + (lane & 15);
      int t = (it + row) * B + b;
      vec_bf[(size_t)t * D + n * 64 + d] = f2b(acc_v[mi][r] * rinv_s[row]);
    }
}

// ------- fused split-K reduce + bias + residual + layernorm -> h, h_bf --------
// wave-shuffle reductions: 2 barriers
template <int P, int HASBIAS>
__global__ __launch_bounds__(256) void add_ln_reduce(const float* __restrict__ part,
                                                     const float* __restrict__ bias,
                                                     float* __restrict__ h,
                                                     unsigned short* __restrict__ h_bf,
                                                     const float* __restrict__ g,
                                                     const float* __restrict__ bi) {
  int t = blockIdx.x;
  int tid = threadIdx.x;
  int wv = tid >> 6, lane = tid & 63;
  __shared__ float red[8];
  float vx = 0.f, vy = 0.f, vz = 0.f, vw = 0.f;
  float s = 0.0f;
  int c = tid * 4;
  if (tid < 192) {
    float4 x = {0.f, 0.f, 0.f, 0.f};
#pragma unroll
    for (int p = 0; p < P; ++p) {
      float4 pp = *(const float4*)&part[(size_t)p * NTOK * D + (size_t)t * D + c];
      x.x += pp.x; x.y += pp.y; x.z += pp.z; x.w += pp.w;
    }
    if (HASBIAS) {
      float4 bb = *(const float4*)&bias[c];
      x.x += bb.x; x.y += bb.y; x.z += bb.z; x.w += bb.w;
    }
    float4 hh = *(const float4*)&h[(size_t)t * D + c];
    vx = x.x + hh.x; vy = x.y + hh.y; vz = x.z + hh.z; vw = x.w + hh.w;
    s = vx + vy + vz + vw;
  }
#pragma unroll
  for (int m = 1; m < 64; m <<= 1) s += __shfl_xor(s, m, 64);
  if (lane == 0) red[wv] = s;
  __syncthreads();
  float mu = (red[0] + red[1] + red[2] + red[3]) * (1.0f / (float)D);
  float s2 = 0.0f;
  if (tid < 192) {
    float dx = vx - mu, dy = vy - mu, dz = vz - mu, dw = vw - mu;
    s2 = dx * dx + dy * dy + dz * dz + dw * dw;
  }
#pragma unroll
  for (int m = 1; m < 64; m <<= 1) s2 += __shfl_xor(s2, m, 64);
  if (lane == 0) red[4 + wv] = s2;
  __syncthreads();
  float var = (red[4] + red[5] + red[6] + red[7]) * (1.0f / (float)D);
  float rstd = rsqrtf(var + 1e-3f);
  if (tid < 192) {
    float4 gg = *(const float4*)&g[c];
    float4 bb = *(const float4*)&bi[c];
    float o0 = (vx - mu) * rstd * gg.x + bb.x;
    float o1 = (vy - mu) * rstd * gg.y + bb.y;
    float o2 = (vz - mu) * rstd * gg.z + bb.z;
    float o3 = (vw - mu) * rstd * gg.w + bb.w;
    float4 of = {o0, o1, o2, o3};
    *(float4*)&h[(size_t)t * D + c] = of;
    ushort4 ob;
    ob.x = f2b(o0); ob.y = f2b(o1); ob.z = f2b(o2); ob.w = f2b(o3);
    *(ushort4*)&h_bf[(size_t)t * D + c] = ob;
  }
}

extern "C" void kernel_launch(void* const* d_in, const int* in_sizes, int n_in,
                              void* d_out, int out_size, void* d_ws, size_t ws_size,
                              hipStream_t stream) {
  const int*   inp_k      = (const int*)d_in[0];
  const int*   seg_ids    = (const int*)d_in[1];
  const int*   input_mask = (const int*)d_in[2];
  const float* lut        = (const float*)d_in[3];
  const float* Wq         = (const float*)d_in[4];
  const float* Wk         = (const float*)d_in[5];
  const float* Wv         = (const float*)d_in[6];
  const float* Wr         = (const float*)d_in[7];
  const float* Wo         = (const float*)d_in[8];
  const float* r_w_bias   = (const float*)d_in[9];
  const float* r_r_bias   = (const float*)d_in[10];
  const float* r_s_bias   = (const float*)d_in[11];
  const float* seg_embed  = (const float*)d_in[12];
  const float* ln_attn_g  = (const float*)d_in[13];
  const float* ln_attn_b  = (const float*)d_in[14];
  const float* ln_ff_g    = (const float*)d_in[15];
  const float* ln_ff_b    = (const float*)d_in[16];
  const float* ff_w1      = (const float*)d_in[17];
  const float* ff_b1      = (const float*)d_in[18];
  const float* ff_w2      = (const float*)d_in[19];
  const float* ff_b2      = (const float*)d_in[20];

  float* h = (float*)d_out;
  char* wp = (char*)d_ws;
  auto alloc = [&](size_t bytes) -> void* {
    void* p = (void*)wp;
    wp += (bytes + 255) & ~(size_t)255;
    return p;
  };
  const size_t TOKD = (size_t)NTOK * D;
  const size_t DD = (size_t)D * D;
  const size_t DDI = (size_t)D * DI;
  unsigned short* qkv_bf = (unsigned short*)alloc((size_t)NTOK * 2304 * 2);
  unsigned short* kr_all = (unsigned short*)alloc((size_t)NL * TOKD * 2);
  unsigned short* h_bf   = (unsigned short*)alloc(TOKD * 2);
  unsigned short* r2_bf  = (unsigned short*)alloc(TOKD * 2);
  unsigned short* vec_bf = (unsigned short*)alloc(TOKD * 2);
  unsigned short* ff1_bf = (unsigned short*)alloc((size_t)NTOK * DI * 2);
  float* part = (float*)alloc((size_t)4 * TOKD * 4);
  unsigned short* wqkv_t = (unsigned short*)alloc((size_t)NL * 3 * DD * 2);
  unsigned short* wr_t   = (unsigned short*)alloc((size_t)NL * DD * 2);
  unsigned short* wo_t   = (unsigned short*)alloc((size_t)NL * DD * 2);
  unsigned short* w1_t   = (unsigned short*)alloc((size_t)NL * DDI * 2);
  unsigned short* w2_t   = (unsigned short*)alloc((size_t)NL * DDI * 2);

  prep_all<<<NL * 1872, 256, 0, stream>>>(Wq, Wk, Wv, Wr, Wo, ff_w1, ff_w2,
                                          wqkv_t, wr_t, wo_t, w1_t, w2_t);
  embed_kernel<<<NTOK, 256, 0, stream>>>(inp_k, lut, h, h_bf);
  posemb_kernel<<<2 * S, 384, 0, stream>>>(r2_bf);
  gemm_kr_all<<<NL * 96, 256, 0, stream>>>(r2_bf, wr_t, kr_all);

  for (int l = 0; l < NL; ++l) {
    gemm_qkv<<<288, 256, 0, stream>>>(h_bf, wqkv_t + (size_t)l * 3 * DD, qkv_bf);

    attn_kernel<<<dim3(16, B, H), 256, 0, stream>>>(
        qkv_bf, kr_all + (size_t)l * TOKD, seg_ids, input_mask,
        r_w_bias + (size_t)l * D, r_r_bias + (size_t)l * D,
        r_s_bias + (size_t)l * D, seg_embed + (size_t)l * 2 * H * DH,
        vec_bf);

    gemm_splitk<<<dim3(6, 16, 2), 256, 0, stream>>>(
        vec_bf, wo_t + (size_t)l * DD, part, D, D, 384);
    add_ln_reduce<2, 0><<<NTOK, 256, 0, stream>>>(
        part, nullptr, h, h_bf, ln_attn_g + (size_t)l * D, ln_attn_b + (size_t)l * D);

    gemm_bias<1><<<24 * 16, 256, 0, stream>>>(
        h_bf, w1_t + (size_t)l * DDI, ff_b1 + (size_t)l * DI, ff1_bf, DI, D, 24);

    gemm_splitk<<<dim3(6, 16, 3), 256, 0, stream>>>(
        ff1_bf, w2_t + (size_t)l * DDI, part, D, DI, 1024);
    add_ln_reduce<3, 1><<<NTOK, 256, 0, stream>>>(
        part, ff_b2 + (size_t)l * D, h, h_bf, ln_ff_g + (size_t)l * D, ln_ff_b + (size_t)l * D);
  }
}

// Round 14
// 1285.489 us; speedup vs baseline: 1.0220x; 1.0220x over previous
//
#include <hip/hip_runtime.h>
#include <hip/hip_bf16.h>
#include <math.h>

#define S 512
#define B 2
#define D 768
#define H 12
#define DH 64
#define DI 3072
#define NL 12
#define NTOK (S * B)   // 1024

typedef __attribute__((ext_vector_type(8))) short short8v;
typedef __attribute__((ext_vector_type(4))) float f32x4;

__device__ __forceinline__ unsigned short f2b(float f) {
  union { float f; unsigned int u; } v; v.f = f;
  unsigned int r = v.u + 0x7fffu + ((v.u >> 16) & 1u);
  return (unsigned short)(r >> 16);
}
__device__ __forceinline__ float b2f(unsigned short u) {
  union { unsigned int u; float f; } v; v.u = ((unsigned int)u) << 16;
  return v.f;
}

__device__ __forceinline__ float gelu_f(float x) {
  const float c = 0.7978845608028654f;  // sqrt(2/pi)
  float t = tanhf(c * (x + 0.044715f * x * x * x));
  return x * 0.5f * (1.0f + t);
}

// xor swizzle key for bf16 LDS tiles with 64-ushort rows (8-ushort granular)
__device__ __forceinline__ int vkey(int r) {
  return ((((r & 7) ^ ((r >> 3) & 7)) & 7) << 3);
}

// ---------------- embedding gather ----------------
__global__ __launch_bounds__(256) void embed_kernel(const int* __restrict__ inp_k,
                                                    const float* __restrict__ lut,
                                                    float* __restrict__ h,
                                                    unsigned short* __restrict__ h_bf) {
  int t = blockIdx.x;
  int id = inp_k[t];
  for (int j = threadIdx.x; j < D; j += 256) {
    float v = lut[(size_t)id * D + j];
    h[t * D + j] = v;
    h_bf[t * D + j] = f2b(v);
  }
}

// ---------------- positional embedding -> bf16 [2S, D] ----------------
__global__ __launch_bounds__(384) void posemb_kernel(unsigned short* __restrict__ r2b) {
  int j = blockIdx.x;
  int d = threadIdx.x;
  float pos = (float)(S - j);
  float inv_freq = expf(-logf(10000.0f) * (2.0f * (float)d / (float)D));
  float x = pos * inv_freq;
  r2b[j * D + d]       = f2b(sinf(x));
  r2b[j * D + 384 + d] = f2b(cosf(x));
}

// ===== weight prep: coalesced f32 reads + conflict-free LDS transpose =========
__device__ __forceinline__ void transpose_swz(const float* __restrict__ src,   // [K][N] row-major
                                              unsigned short* __restrict__ dst,
                                              int K, int N, int tile, int n_base,
                                              float* __restrict__ Ls /*[64*65]*/) {
  int ntk = K >> 6;
  int tk = tile % ntk, tn = tile / ntk;
  int k0 = tk << 6, n0 = tn << 6;
  int tid = threadIdx.x;
  int rr = tid >> 4, c4 = (tid & 15) * 4;
#pragma unroll
  for (int r = 0; r < 4; ++r) {
    int k = rr + r * 16;
    float4 a = *(const float4*)&src[(size_t)(k0 + k) * N + n0 + c4];
    Ls[(c4 + 0) * 65 + k] = a.x;
    Ls[(c4 + 1) * 65 + k] = a.y;
    Ls[(c4 + 2) * 65 + k] = a.z;
    Ls[(c4 + 3) * 65 + k] = a.w;
  }
  __syncthreads();
  int nl = tid >> 2, kc0 = (tid & 3) << 4;
  float f[16];
#pragma unroll
  for (int c = 0; c < 16; ++c) f[c] = Ls[nl * 65 + kc0 + c];
  short8v v0, v1;
#pragma unroll
  for (int e = 0; e < 8; ++e) {
    v0[e] = (short)f2b(f[e]);
    v1[e] = (short)f2b(f[8 + e]);
  }
  int ng = n_base + n0;
  size_t tilebase = ((size_t)(ng >> 7) * ntk + tk) * 8192;
  int row = (ng & 64) + nl;
  int key = (row & 7) << 3;
  *(short8v*)&dst[tilebase + row * 64 + (kc0 ^ key)] = v0;
  *(short8v*)&dst[tilebase + row * 64 + ((kc0 + 8) ^ key)] = v1;
}

// per layer: 432 qkv + 144 wr + 576 w1 + 576 w2 + 144 wo = 1872 blocks
__global__ __launch_bounds__(256) void prep_all(const float* __restrict__ Wq,
                                                const float* __restrict__ Wk,
                                                const float* __restrict__ Wv,
                                                const float* __restrict__ Wr,
                                                const float* __restrict__ Wo,
                                                const float* __restrict__ W1,
                                                const float* __restrict__ W2,
                                                unsigned short* __restrict__ wqkv_t,
                                                unsigned short* __restrict__ wr_t,
                                                unsigned short* __restrict__ wo_t,
                                                unsigned short* __restrict__ w1_t,
                                                unsigned short* __restrict__ w2_t) {
  __shared__ float Ls[64 * 65];
  const size_t DD = (size_t)D * D;
  const size_t DDI = (size_t)D * DI;
  int tb = blockIdx.x;
  int l = tb / 1872, t2 = tb % 1872;
  int tid = threadIdx.x;
  if (t2 < 432) {
    int which = t2 / 144, tile = t2 % 144;
    const float* src = (which == 0 ? Wq : (which == 1 ? Wk : Wv)) + l * DD;
    transpose_swz(src, wqkv_t + l * 3 * DD, D, D, tile, which * D, Ls);
  } else if (t2 < 576) {
    transpose_swz(Wr + l * DD, wr_t + l * DD, D, D, t2 - 432, 0, Ls);
  } else if (t2 < 1152) {
    transpose_swz(W1 + l * DDI, w1_t + l * DDI, D, DI, t2 - 576, 0, Ls);
  } else if (t2 < 1728) {
    transpose_swz(W2 + l * DDI, w2_t + l * DDI, DI, D, t2 - 1152, 0, Ls);
  } else {
    // Wo: already [N][K]; swizzle-copy
    int c = t2 - 1728;
    int tkk = c % 12, tnn = c / 12;
    int k0 = tkk << 6, n0 = tnn << 6;
    int nl = tid >> 2, kc0 = (tid & 3) << 4;
    const float* srcp = Wo + l * DD + (size_t)(n0 + nl) * D + k0 + kc0;
    float4 a0 = *(const float4*)&srcp[0];
    float4 a1 = *(const float4*)&srcp[4];
    float4 a2 = *(const float4*)&srcp[8];
    float4 a3 = *(const float4*)&srcp[12];
    short8v v0, v1;
    v0[0] = (short)f2b(a0.x); v0[1] = (short)f2b(a0.y); v0[2] = (short)f2b(a0.z); v0[3] = (short)f2b(a0.w);
    v0[4] = (short)f2b(a1.x); v0[5] = (short)f2b(a1.y); v0[6] = (short)f2b(a1.z); v0[7] = (short)f2b(a1.w);
    v1[0] = (short)f2b(a2.x); v1[1] = (short)f2b(a2.y); v1[2] = (short)f2b(a2.z); v1[3] = (short)f2b(a2.w);
    v1[4] = (short)f2b(a3.x); v1[5] = (short)f2b(a3.y); v1[6] = (short)f2b(a3.z); v1[7] = (short)f2b(a3.w);
    unsigned short* dst = wo_t + l * DD;
    size_t tilebase = ((size_t)(n0 >> 7) * 12 + tkk) * 8192;
    int row = (n0 & 64) + nl;
    int key = (row & 7) << 3;
    *(short8v*)&dst[tilebase + row * 64 + (kc0 ^ key)] = v0;
    *(short8v*)&dst[tilebase + row * 64 + ((kc0 + 8) ^ key)] = v1;
  }
}

// ======================= MFMA GEMM (global_load_lds + swizzle) ================
template <int ACT, int OUTBF>
__device__ __forceinline__ void gemm_tile(const unsigned short* __restrict__ A,
                                          const unsigned short* __restrict__ Wt,
                                          const float* __restrict__ bias,
                                          float* __restrict__ Cf,
                                          unsigned short* __restrict__ Cb,
                                          int N, int K, int bm, int bn,
                                          int kbeg, int kend) {
  __shared__ __align__(16) unsigned short As[64 * 64];
  __shared__ __align__(16) unsigned short Bs[128 * 64];
  const int tid = threadIdx.x, lane = tid & 63, w = tid >> 6;
  const int l8 = lane >> 3, lm8 = lane & 7;
  const int aColByte = ((lm8 ^ l8) << 4);
  const int KT = K >> 6;
  const size_t wtn = (size_t)(bn >> 7) * KT;

  f32x4 acc[4][2];
#pragma unroll
  for (int mi = 0; mi < 4; ++mi)
#pragma unroll
    for (int ni = 0; ni < 2; ++ni)
      acc[mi][ni] = (f32x4){0.f, 0.f, 0.f, 0.f};

  for (int kt = kbeg; kt < kend; kt += 64) {
    __syncthreads();
#pragma unroll
    for (int c = 0; c < 2; ++c) {
      int row = c * 32 + w * 8 + l8;
      const char* src = (const char*)&A[(size_t)(bm + row) * K + kt] + aColByte;
      __builtin_amdgcn_global_load_lds(
          (const __attribute__((address_space(1))) void*)src,
          (__attribute__((address_space(3))) void*)((char*)As + c * 4096 + w * 1024),
          16, 0, 0);
    }
    const char* wt = (const char*)&Wt[(wtn + (kt >> 6)) * 8192];
#pragma unroll
    for (int c = 0; c < 4; ++c) {
      __builtin_amdgcn_global_load_lds(
          (const __attribute__((address_space(1))) void*)(wt + c * 4096 + w * 1024 + lane * 16),
          (__attribute__((address_space(3))) void*)((char*)Bs + c * 4096 + w * 1024),
          16, 0, 0);
    }
    __syncthreads();
#pragma unroll
    for (int ks = 0; ks < 2; ++ks) {
      const int kus = ks * 32 + (lane >> 4) * 8;
      short8v af[4], bf[2];
#pragma unroll
      for (int mi = 0; mi < 4; ++mi) {
        int row = mi * 16 + (lane & 15);
        af[mi] = *(const short8v*)&As[row * 64 + (kus ^ ((row & 7) << 3))];
      }
#pragma unroll
      for (int ni = 0; ni < 2; ++ni) {
        int row = w * 32 + ni * 16 + (lane & 15);
        bf[ni] = *(const short8v*)&Bs[row * 64 + (kus ^ ((row & 7) << 3))];
      }
#pragma unroll
      for (int mi = 0; mi < 4; ++mi)
#pragma unroll
        for (int ni = 0; ni < 2; ++ni)
          acc[mi][ni] = __builtin_amdgcn_mfma_f32_16x16x32_bf16(af[mi], bf[ni], acc[mi][ni], 0, 0, 0);
    }
  }

  int r0 = (lane >> 4) * 4, cc = lane & 15;
#pragma unroll
  for (int mi = 0; mi < 4; ++mi) {
    int row = bm + mi * 16 + r0;
#pragma unroll
    for (int ni = 0; ni < 2; ++ni) {
      int col = bn + w * 32 + ni * 16 + cc;
      float bv = bias ? bias[col] : 0.0f;
#pragma unroll
      for (int r = 0; r < 4; ++r) {
        float v = acc[mi][ni][r] + bv;
        if (ACT == 1) v = gelu_f(v);
        if (OUTBF) Cb[(size_t)(row + r) * N + col] = f2b(v);
        else       Cf[(size_t)(row + r) * N + col] = v;
      }
    }
  }
}

// qkv projection only: grid.x = 288
__global__ __launch_bounds__(256) void gemm_qkv(const unsigned short* __restrict__ h_bf,
                                                const unsigned short* __restrict__ wqkv,
                                                unsigned short* __restrict__ qkv_bf) {
  int bx = blockIdx.x;
  gemm_tile<0, 1>(h_bf, wqkv, nullptr, nullptr, qkv_bf, 2304, 768,
                  (bx / 18) * 64, (bx % 18) * 128, 0, 768);
}

// kr projections for ALL layers upfront: grid.x = 12 * 96 = 1152
__global__ __launch_bounds__(256) void gemm_kr_all(const unsigned short* __restrict__ r2_bf,
                                                   const unsigned short* __restrict__ wr_t,
                                                   unsigned short* __restrict__ kr_all) {
  int bx = blockIdx.x;
  int l = bx / 96, b2 = bx % 96;
  gemm_tile<0, 1>(r2_bf, wr_t + (size_t)l * D * D, nullptr, nullptr,
                  kr_all + (size_t)l * NTOK * D, 768, 768,
                  (b2 / 6) * 64, (b2 % 6) * 128, 0, 768);
}

template <int ACT>
__global__ __launch_bounds__(256) void gemm_bias(const unsigned short* __restrict__ A,
                                                 const unsigned short* __restrict__ W,
                                                 const float* __restrict__ bias,
                                                 unsigned short* __restrict__ C,
                                                 int N, int K, int ncb) {
  int bx = blockIdx.x;
  gemm_tile<ACT, 1>(A, W, bias, nullptr, C, N, K, (bx / ncb) * 64, (bx % ncb) * 128, 0, K);
}

__global__ __launch_bounds__(256) void gemm_splitk(const unsigned short* __restrict__ A,
                                                   const unsigned short* __restrict__ W,
                                                   float* __restrict__ part,
                                                   int N, int K, int kch) {
  int kz = blockIdx.z;
  float* Cf = part + (size_t)kz * NTOK * N;
  gemm_tile<0, 0>(A, W, nullptr, Cf, nullptr, N, K,
                  blockIdx.y * 64, blockIdx.x * 128, kz * kch, (kz + 1) * kch);
}

// ============ MFMA fused attention, 32-row i-tile, online softmax =============
__global__ __launch_bounds__(256) void attn_kernel(const unsigned short* __restrict__ qkv,
                                                   const unsigned short* __restrict__ krb,
                                                   const int* __restrict__ seg_ids,
                                                   const int* __restrict__ input_mask,
                                                   const float* __restrict__ rwb,
                                                   const float* __restrict__ rrb,
                                                   const float* __restrict__ rsb,
                                                   const float* __restrict__ segemb,
                                                   unsigned short* __restrict__ vec_bf) {
  __shared__ __align__(16) char smem[51840];
  unsigned short* qw_s = (unsigned short*)(smem + 0);       // [32][72]
  unsigned short* qr_s = (unsigned short*)(smem + 4608);    // [32][72]
  unsigned short* k_s  = (unsigned short*)(smem + 9216);    // [64][72]
  unsigned short* kr_s = (unsigned short*)(smem + 18432);   // [96][72]
  unsigned short* bd_s = (unsigned short*)(smem + 32256);   // [32][104]
  unsigned short* vt_s = (unsigned short*)(smem + 38912);   // [64][64] xor
  unsigned short* pb_s = (unsigned short*)(smem + 47104);   // [32][64] xor
  float* sc_s  = (float*)(smem + 9216);                     // [32][68] f32, aliases k_s
  float* efs    = (float*)(smem + 51200);                   // [2][32]
  float* frow_s = (float*)(smem + 51456);                   // [32]
  float* rinv_s = (float*)(smem + 51584);                   // [32]
  int*   segrow = (int*)(smem + 51712);                     // [32]

  const int it = blockIdx.x * 32, b = blockIdx.y, n = blockIdx.z;
  const int tid = threadIdx.x, lane = tid & 63, w = tid >> 6;

  {
    int il = tid >> 3, d8 = (tid & 7) * 8;
    int t = (it + il) * B + b;
    short8v q0 = *(const short8v*)&qkv[(size_t)t * 2304 + n * 64 + d8];
    short8v ow0, or0;
#pragma unroll
    for (int e = 0; e < 8; ++e) {
      float f0 = b2f((unsigned short)q0[e]);
      ow0[e] = (short)f2b(f0 + rwb[n * 64 + d8 + e]);
      or0[e] = (short)f2b(f0 + rrb[n * 64 + d8 + e]);
    }
    *(short8v*)&qw_s[il * 72 + d8] = ow0;
    *(short8v*)&qr_s[il * 72 + d8] = or0;
  }
  if (tid < 64) {
    int il = tid >> 1, s = tid & 1;
    int t = (it + il) * B + b;
    float acc = 0.0f;
    for (int d = 0; d < 64; ++d)
      acc = fmaf(b2f(qkv[(size_t)t * 2304 + n * 64 + d]) + rsb[n * 64 + d],
                 segemb[(s * H + n) * 64 + d], acc);
    efs[s * 32 + il] = acc;
  }
  if (tid < 32) segrow[tid] = seg_ids[(it + tid) * B + b];

  {
#pragma unroll
    for (int c = 0; c < 2; ++c) {
      int idx = tid + c * 256;
      int row = idx >> 3, k8 = (idx & 7) * 8;
      *(short8v*)&k_s[row * 72 + k8] =
          *(const short8v*)&qkv[(size_t)(row * B + b) * 2304 + 768 + n * 64 + k8];
    }
    int u0 = 481 - it;
#pragma unroll
    for (int c = 0; c < 3; ++c) {
      int idx = tid + c * 256;
      int row = idx >> 3, k8 = (idx & 7) * 8;
      *(short8v*)&kr_s[row * 72 + k8] =
          *(const short8v*)&krb[(size_t)(u0 + row) * 768 + n * 64 + k8];
    }
  }

  f32x4 acc_v[2];
  acc_v[0] = (f32x4){0.f, 0.f, 0.f, 0.f};
  acc_v[1] = (f32x4){0.f, 0.f, 0.f, 0.f};
  float m_run = -3.0e38f;
  float rsq = 0.0f;
  const int srow = tid >> 3, sc0 = (tid & 7) * 8;

  __syncthreads();   // T1

  for (int jt = 0; jt < 512; jt += 64) {
    const int vj = tid >> 2, vd16 = (tid & 3) * 16;
    short8v vl0 = *(const short8v*)&qkv[(size_t)((jt + vj) * B + b) * 2304 + 1536 + n * 64 + vd16];
    short8v vl1 = *(const short8v*)&qkv[(size_t)((jt + vj) * B + b) * 2304 + 1536 + n * 64 + vd16 + 8];

    f32x4 jacc[3][2];
#pragma unroll
    for (int t = 0; t < 3; ++t) {
      jacc[t][0] = (f32x4){0.f, 0.f, 0.f, 0.f};
      jacc[t][1] = (f32x4){0.f, 0.f, 0.f, 0.f};
    }
#pragma unroll
    for (int ks = 0; ks < 2; ++ks) {
      int kb = ks * 32 + (lane >> 4) * 8;
      short8v aw[2], ar[2];
#pragma unroll
      for (int mi = 0; mi < 2; ++mi) {
        aw[mi] = *(const short8v*)&qw_s[(mi * 16 + (lane & 15)) * 72 + kb];
        ar[mi] = *(const short8v*)&qr_s[(mi * 16 + (lane & 15)) * 72 + kb];
      }
      {
        short8v bk = *(const short8v*)&k_s[(w * 16 + (lane & 15)) * 72 + kb];
        jacc[0][0] = __builtin_amdgcn_mfma_f32_16x16x32_bf16(aw[0], bk, jacc[0][0], 0, 0, 0);
        jacc[0][1] = __builtin_amdgcn_mfma_f32_16x16x32_bf16(aw[1], bk, jacc[0][1], 0, 0, 0);
      }
      {
        short8v br = *(const short8v*)&kr_s[(w * 16 + (lane & 15)) * 72 + kb];
        jacc[1][0] = __builtin_amdgcn_mfma_f32_16x16x32_bf16(ar[0], br, jacc[1][0], 0, 0, 0);
        jacc[1][1] = __builtin_amdgcn_mfma_f32_16x16x32_bf16(ar[1], br, jacc[1][1], 0, 0, 0);
      }
      if (w < 2) {
        short8v br = *(const short8v*)&kr_s[((w + 4) * 16 + (lane & 15)) * 72 + kb];
        jacc[2][0] = __builtin_amdgcn_mfma_f32_16x16x32_bf16(ar[0], br, jacc[2][0], 0, 0, 0);
        jacc[2][1] = __builtin_amdgcn_mfma_f32_16x16x32_bf16(ar[1], br, jacc[2][1], 0, 0, 0);
      }
    }
#pragma unroll
    for (int t = 1; t < 3; ++t) {
      int cf = w + (t - 1) * 4;
      if (t == 1 || w < 2) {
#pragma unroll
        for (int mi = 0; mi < 2; ++mi)
#pragma unroll
          for (int r = 0; r < 4; ++r)
            bd_s[(mi * 16 + (lane >> 4) * 4 + r) * 104 + cf * 16 + (lane & 15)] =
                f2b(jacc[t][mi][r]);
      }
    }
    __syncthreads();   // T2

    {
      int jl = w * 16 + (lane & 15);
      int jg = jt + jl;
      float maskterm = -1e30f * (float)input_mask[jg * B + b];
      int segj = seg_ids[jg * B + b];
#pragma unroll
      for (int mi = 0; mi < 2; ++mi)
#pragma unroll
        for (int r = 0; r < 4; ++r) {
          int il = mi * 16 + (lane >> 4) * 4 + r;
          float bd = b2f(bd_s[il * 104 + 31 - il + jl]);
          float e = efs[(segrow[il] != segj ? 1 : 0) * 32 + il];
          sc_s[il * 68 + jl] = (jacc[0][mi][r] + bd + e) * 0.125f + maskterm;
        }
    }
    __syncthreads();   // T3

    {
      float4 f0 = *(const float4*)&sc_s[srow * 68 + sc0];
      float4 f1 = *(const float4*)&sc_s[srow * 68 + sc0 + 4];
      float mx = fmaxf(fmaxf(fmaxf(f0.x, f0.y), fmaxf(f0.z, f0.w)),
                       fmaxf(fmaxf(f1.x, f1.y), fmaxf(f1.z, f1.w)));
      mx = fmaxf(mx, __shfl_xor(mx, 1, 8));
      mx = fmaxf(mx, __shfl_xor(mx, 2, 8));
      mx = fmaxf(mx, __shfl_xor(mx, 4, 8));
      float mnew = fmaxf(m_run, mx);
      float fsc = __expf(m_run - mnew);
      m_run = mnew;
      float p0 = __expf(f0.x - mnew), p1 = __expf(f0.y - mnew);
      float p2 = __expf(f0.z - mnew), p3 = __expf(f0.w - mnew);
      float p4 = __expf(f1.x - mnew), p5 = __expf(f1.y - mnew);
      float p6 = __expf(f1.z - mnew), p7 = __expf(f1.w - mnew);
      rsq = rsq * fsc + ((p0 + p1 + p2 + p3) + (p4 + p5 + p6 + p7));
      short8v o0;
      o0[0] = (short)f2b(p0); o0[1] = (short)f2b(p1); o0[2] = (short)f2b(p2); o0[3] = (short)f2b(p3);
      o0[4] = (short)f2b(p4); o0[5] = (short)f2b(p5); o0[6] = (short)f2b(p6); o0[7] = (short)f2b(p7);
      *(short8v*)&pb_s[srow * 64 + (sc0 ^ vkey(srow))] = o0;
      if ((tid & 7) == 0) frow_s[srow] = fsc;
#pragma unroll
      for (int e = 0; e < 8; ++e) {
        int d0 = vd16 + e, d1 = vd16 + 8 + e;
        vt_s[d0 * 64 + (vj ^ vkey(d0))] = (unsigned short)vl0[e];
        vt_s[d1 * 64 + (vj ^ vkey(d1))] = (unsigned short)vl1[e];
      }
    }
    __syncthreads();   // T4

#pragma unroll
    for (int mi = 0; mi < 2; ++mi) {
#pragma unroll
      for (int r = 0; r < 4; ++r)
        acc_v[mi][r] *= frow_s[mi * 16 + (lane >> 4) * 4 + r];
    }
#pragma unroll
    for (int ks = 0; ks < 2; ++ks) {
      int kb = ks * 32 + (lane >> 4) * 8;
      int vrow = w * 16 + (lane & 15);
      short8v bv = *(const short8v*)&vt_s[vrow * 64 + (kb ^ vkey(vrow))];
#pragma unroll
      for (int mi = 0; mi < 2; ++mi) {
        int prow = mi * 16 + (lane & 15);
        short8v ap = *(const short8v*)&pb_s[prow * 64 + (kb ^ vkey(prow))];
        acc_v[mi] = __builtin_amdgcn_mfma_f32_16x16x32_bf16(ap, bv, acc_v[mi], 0, 0, 0);
      }
    }
    if (jt < 448) {
      int jn = jt + 64;
#pragma unroll
      for (int c = 0; c < 2; ++c) {
        int idx = tid + c * 256;
        int row = idx >> 3, k8 = (idx & 7) * 8;
        *(short8v*)&k_s[row * 72 + k8] =
            *(const short8v*)&qkv[(size_t)((jn + row) * B + b) * 2304 + 768 + n * 64 + k8];
      }
      int u0 = 481 - it + jn;
#pragma unroll
      for (int c = 0; c < 3; ++c) {
        int idx = tid + c * 256;
        int row = idx >> 3, k8 = (idx & 7) * 8;
        *(short8v*)&kr_s[row * 72 + k8] =
            *(const short8v*)&krb[(size_t)(u0 + row) * 768 + n * 64 + k8];
      }
    }
    __syncthreads();   // T1 (next)
  }

  {
    float tot = rsq;
    tot += __shfl_xor(tot, 1, 8);
    tot += __shfl_xor(tot, 2, 8);
    tot += __shfl_xor(tot, 4, 8);
    if ((tid & 7) == 0) rinv_s[srow] = 1.0f / tot;
  }
  __syncthreads();

#pragma unroll
  for (int mi = 0; mi < 2; ++mi)
#pragma unroll
    for (int r = 0; r < 4; ++r) {
      int row = mi * 16 + (lane >> 4) * 4 + r;
      int d = w * 16 + (lane & 15);
      int t = (it + row) * B + b;
      vec_bf[(size_t)t * D + n * 64 + d] = f2b(acc_v[mi][r] * rinv_s[row]);
    }
}

// ------- fused split-K reduce + bias + residual + layernorm -> h, h_bf --------
// wave-shuffle reductions: 2 barriers
template <int P, int HASBIAS>
__global__ __launch_bounds__(256) void add_ln_reduce(const float* __restrict__ part,
                                                     const float* __restrict__ bias,
                                                     float* __restrict__ h,
                                                     unsigned short* __restrict__ h_bf,
                                                     const float* __restrict__ g,
                                                     const float* __restrict__ bi) {
  int t = blockIdx.x;
  int tid = threadIdx.x;
  int wv = tid >> 6, lane = tid & 63;
  __shared__ float red[8];
  float vx = 0.f, vy = 0.f, vz = 0.f, vw = 0.f;
  float s = 0.0f;
  int c = tid * 4;
  if (tid < 192) {
    float4 x = {0.f, 0.f, 0.f, 0.f};
#pragma unroll
    for (int p = 0; p < P; ++p) {
      float4 pp = *(const float4*)&part[(size_t)p * NTOK * D + (size_t)t * D + c];
      x.x += pp.x; x.y += pp.y; x.z += pp.z; x.w += pp.w;
    }
    if (HASBIAS) {
      float4 bb = *(const float4*)&bias[c];
      x.x += bb.x; x.y += bb.y; x.z += bb.z; x.w += bb.w;
    }
    float4 hh = *(const float4*)&h[(size_t)t * D + c];
    vx = x.x + hh.x; vy = x.y + hh.y; vz = x.z + hh.z; vw = x.w + hh.w;
    s = vx + vy + vz + vw;
  }
#pragma unroll
  for (int m = 1; m < 64; m <<= 1) s += __shfl_xor(s, m, 64);
  if (lane == 0) red[wv] = s;
  __syncthreads();
  float mu = (red[0] + red[1] + red[2] + red[3]) * (1.0f / (float)D);
  float s2 = 0.0f;
  if (tid < 192) {
    float dx = vx - mu, dy = vy - mu, dz = vz - mu, dw = vw - mu;
    s2 = dx * dx + dy * dy + dz * dz + dw * dw;
  }
#pragma unroll
  for (int m = 1; m < 64; m <<= 1) s2 += __shfl_xor(s2, m, 64);
  if (lane == 0) red[4 + wv] = s2;
  __syncthreads();
  float var = (red[4] + red[5] + red[6] + red[7]) * (1.0f / (float)D);
  float rstd = rsqrtf(var + 1e-3f);
  if (tid < 192) {
    float4 gg = *(const float4*)&g[c];
    float4 bb = *(const float4*)&bi[c];
    float o0 = (vx - mu) * rstd * gg.x + bb.x;
    float o1 = (vy - mu) * rstd * gg.y + bb.y;
    float o2 = (vz - mu) * rstd * gg.z + bb.z;
    float o3 = (vw - mu) * rstd * gg.w + bb.w;
    float4 of = {o0, o1, o2, o3};
    *(float4*)&h[(size_t)t * D + c] = of;
    ushort4 ob;
    ob.x = f2b(o0); ob.y = f2b(o1); ob.z = f2b(o2); ob.w = f2b(o3);
    *(ushort4*)&h_bf[(size_t)t * D + c] = ob;
  }
}

extern "C" void kernel_launch(void* const* d_in, const int* in_sizes, int n_in,
                              void* d_out, int out_size, void* d_ws, size_t ws_size,
                              hipStream_t stream) {
  const int*   inp_k      = (const int*)d_in[0];
  const int*   seg_ids    = (const int*)d_in[1];
  const int*   input_mask = (const int*)d_in[2];
  const float* lut        = (const float*)d_in[3];
  const float* Wq         = (const float*)d_in[4];
  const float* Wk         = (const float*)d_in[5];
  const float* Wv         = (const float*)d_in[6];
  const float* Wr         = (const float*)d_in[7];
  const float* Wo         = (const float*)d_in[8];
  const float* r_w_bias   = (const float*)d_in[9];
  const float* r_r_bias   = (const float*)d_in[10];
  const float* r_s_bias   = (const float*)d_in[11];
  const float* seg_embed  = (const float*)d_in[12];
  const float* ln_attn_g  = (const float*)d_in[13];
  const float* ln_attn_b  = (const float*)d_in[14];
  const float* ln_ff_g    = (const float*)d_in[15];
  const float* ln_ff_b    = (const float*)d_in[16];
  const float* ff_w1      = (const float*)d_in[17];
  const float* ff_b1      = (const float*)d_in[18];
  const float* ff_w2      = (const float*)d_in[19];
  const float* ff_b2      = (const float*)d_in[20];

  float* h = (float*)d_out;
  char* wp = (char*)d_ws;
  auto alloc = [&](size_t bytes) -> void* {
    void* p = (void*)wp;
    wp += (bytes + 255) & ~(size_t)255;
    return p;
  };
  const size_t TOKD = (size_t)NTOK * D;
  const size_t DD = (size_t)D * D;
  const size_t DDI = (size_t)D * DI;
  unsigned short* qkv_bf = (unsigned short*)alloc((size_t)NTOK * 2304 * 2);
  unsigned short* kr_all = (unsigned short*)alloc((size_t)NL * TOKD * 2);
  unsigned short* h_bf   = (unsigned short*)alloc(TOKD * 2);
  unsigned short* r2_bf  = (unsigned short*)alloc(TOKD * 2);
  unsigned short* vec_bf = (unsigned short*)alloc(TOKD * 2);
  unsigned short* ff1_bf = (unsigned short*)alloc((size_t)NTOK * DI * 2);
  float* part = (float*)alloc((size_t)4 * TOKD * 4);
  unsigned short* wqkv_t = (unsigned short*)alloc((size_t)NL * 3 * DD * 2);
  unsigned short* wr_t   = (unsigned short*)alloc((size_t)NL * DD * 2);
  unsigned short* wo_t   = (unsigned short*)alloc((size_t)NL * DD * 2);
  unsigned short* w1_t   = (unsigned short*)alloc((size_t)NL * DDI * 2);
  unsigned short* w2_t   = (unsigned short*)alloc((size_t)NL * DDI * 2);

  prep_all<<<NL * 1872, 256, 0, stream>>>(Wq, Wk, Wv, Wr, Wo, ff_w1, ff_w2,
                                          wqkv_t, wr_t, wo_t, w1_t, w2_t);
  embed_kernel<<<NTOK, 256, 0, stream>>>(inp_k, lut, h, h_bf);
  posemb_kernel<<<2 * S, 384, 0, stream>>>(r2_bf);
  gemm_kr_all<<<NL * 96, 256, 0, stream>>>(r2_bf, wr_t, kr_all);

  for (int l = 0; l < NL; ++l) {
    gemm_qkv<<<288, 256, 0, stream>>>(h_bf, wqkv_t + (size_t)l * 3 * DD, qkv_bf);

    attn_kernel<<<dim3(16, B, H), 256, 0, stream>>>(
        qkv_bf, kr_all + (size_t)l * TOKD, seg_ids, input_mask,
        r_w_bias + (size_t)l * D, r_r_bias + (size_t)l * D,
        r_s_bias + (size_t)l * D, seg_embed + (size_t)l * 2 * H * DH,
        vec_bf);

    gemm_splitk<<<dim3(6, 16, 2), 256, 0, stream>>>(
        vec_bf, wo_t + (size_t)l * DD, part, D, D, 384);
    add_ln_reduce<2, 0><<<NTOK, 256, 0, stream>>>(
        part, nullptr, h, h_bf, ln_attn_g + (size_t)l * D, ln_attn_b + (size_t)l * D);

    gemm_bias<1><<<24 * 16, 256, 0, stream>>>(
        h_bf, w1_t + (size_t)l * DDI, ff_b1 + (size_t)l * DI, ff1_bf, DI, D, 24);

    gemm_splitk<<<dim3(6, 16, 4), 256, 0, stream>>>(
        ff1_bf, w2_t + (size_t)l * DDI, part, D, DI, 768);
    add_ln_reduce<4, 1><<<NTOK, 256, 0, stream>>>(
        part, ff_b2 + (size_t)l * D, h, h_bf, ln_ff_g + (size_t)l * D, ln_ff_b + (size_t)l * D);
  }
}